// Round 5
// baseline (195.268 us; speedup 1.0000x reference)
//
#include <hip/hip_runtime.h>

// Problem constants (B,N,C) = (32,1024,768), H=32
#define BB 32
#define NN 1024
#define CC 768
#define HH 32
#define NCHUNK 32
#define NPER (NN / NCHUNK)     // 32 rows per chunk
#define C4 (CC / 4)            // 192 float4 per row
#define NORB 272               // canonical orbits per batch: r<=c, r<=15, r+c<=31
#define OPB 4                  // orbits per merge block
#define MBLK (NORB / OPB)      // 68 merge blocks per batch

typedef float f32x4 __attribute__((ext_vector_type(4)));

// ---------------------------------------------------------------------------
// K1: fused pool + W-dot. For each (b, n-chunk of 32 rows):
//   s[c] = sum_{n in chunk} x[b,n,c]
//   partW[b][ch][k] = sum_c s[c] * W[k][c]   (one f32x4 per block)
// grid: BB*NCHUNK blocks x 192 threads. Side effect: x ends up L3-resident.
// ---------------------------------------------------------------------------
__global__ void pool_dot(const f32x4* __restrict__ x4,
                         const f32x4* __restrict__ W4,
                         f32x4* __restrict__ partW4) {
    const int blk = blockIdx.x;          // b*NCHUNK + ch
    const int t   = threadIdx.x;         // 0..191 (c4)
    const f32x4* xb = x4 + (size_t)blk * (NPER * C4) + t;
    f32x4 s = {0.f, 0.f, 0.f, 0.f};
#pragma unroll 8
    for (int n = 0; n < NPER; ++n) s += xb[(size_t)n * C4];

    float d[4];
#pragma unroll
    for (int k = 0; k < 4; ++k) {
        const f32x4 w = W4[k * C4 + t];
        d[k] = s.x * w.x + s.y * w.y + s.z * w.z + s.w * w.w;
    }
    const int lane = t & 63;
    const int wid  = t >> 6;
    __shared__ float red[3][4];
#pragma unroll
    for (int k = 0; k < 4; ++k) {
        float v = d[k];
#pragma unroll
        for (int off = 32; off >= 1; off >>= 1) v += __shfl_down(v, off);
        if (lane == 0) red[wid][k] = v;
    }
    __syncthreads();
    if (t == 0) {
        f32x4 w;
        w.x = red[0][0] + red[1][0] + red[2][0];
        w.y = red[0][1] + red[1][1] + red[2][1];
        w.z = red[0][2] + red[1][2] + red[2][2];
        w.w = red[0][3] + red[1][3] + red[2][3];
        partW4[blk] = w;
    }
}

// ---------------------------------------------------------------------------
// K2: orbit merge. Klein-4 orbits {l, T(l), R(l), TR(l)} are closed under the
// 4 source transforms; canonical reps l=r*32+c with r<=c, r<=15, r+c<=31
// (272/batch, enumerated densely -> no dead blocks). Each block handles 4
// orbits: computes alpha from the 32 per-chunk W-dots (512 B, L2-broadcast),
// issues all 16 row loads (reads should hit L3, populated by pool_dot), then
// writes all 16 output rows with NONTEMPORAL stores so the 96 MiB output
// stream does not evict x from L3 mid-kernel.
// grid: BB*MBLK blocks x 192 threads
// ---------------------------------------------------------------------------
__global__ void merge(const f32x4* __restrict__ x4,
                      const f32x4* __restrict__ partW4,
                      const f32x4* __restrict__ bias4,
                      f32x4* __restrict__ o4) {
    const int bidx = blockIdx.x;
    const int b = bidx / MBLK;
    const int j = bidx - b * MBLK;

    // alpha[b] = (1/N) * sum_ch partW[b][ch][:] + bias (uniform across block)
    f32x4 acc = {0.f, 0.f, 0.f, 0.f};
#pragma unroll 8
    for (int ch = 0; ch < NCHUNK; ++ch) acc += partW4[b * NCHUNK + ch];
    const f32x4 al = acc * (1.0f / (float)NN) + bias4[0];
    const float a0 = al.x, a1 = al.y, a2 = al.z, a3 = al.w;

    const int t = threadIdx.x;           // 0..191 (c4)
    const f32x4* xb = x4 + (size_t)b * (NN * C4);
    f32x4* ob = o4 + (size_t)b * (NN * C4);

    // index computation for all 4 orbits (pure VALU, before any load)
    int L[OPB][4];
#pragma unroll
    for (int q = 0; q < OPB; ++q) {
        const int o = OPB * j + q;       // canonical orbit index 0..271
        // invert S(r) = r*(33-r): r = max rr with S(rr) <= o; c = r + o - S(r)
        int r = 0;
#pragma unroll
        for (int rr = 1; rr <= 15; ++rr) if (rr * (33 - rr) <= o) r = rr;
        const int c = r + (o - r * (33 - r));
        L[q][0] = r * HH + c;                    // l
        L[q][1] = c * HH + r;                    // T(l)
        L[q][2] = (NN - 1) - L[q][0];            // R(l)
        L[q][3] = (NN - 1) - L[q][1];            // TR(l)
    }

    // issue all 16 loads before any store (deep vmcnt pipeline)
    f32x4 v[OPB][4];
#pragma unroll
    for (int q = 0; q < OPB; ++q)
#pragma unroll
        for (int m = 0; m < 4; ++m)
            v[q][m] = xb[(size_t)L[q][m] * C4 + t];

#pragma unroll
    for (int q = 0; q < OPB; ++q) {
        // out[row] = a0*x[row] + a1*x[T(row)] + a2*x[R(row)] + a3*x[TR(row)]
        __builtin_nontemporal_store(a0 * v[q][0] + a1 * v[q][1] + a2 * v[q][2] + a3 * v[q][3],
                                    &ob[(size_t)L[q][0] * C4 + t]);
        __builtin_nontemporal_store(a0 * v[q][1] + a1 * v[q][0] + a2 * v[q][3] + a3 * v[q][2],
                                    &ob[(size_t)L[q][1] * C4 + t]);
        __builtin_nontemporal_store(a0 * v[q][2] + a1 * v[q][3] + a2 * v[q][0] + a3 * v[q][1],
                                    &ob[(size_t)L[q][2] * C4 + t]);
        __builtin_nontemporal_store(a0 * v[q][3] + a1 * v[q][2] + a2 * v[q][1] + a3 * v[q][0],
                                    &ob[(size_t)L[q][3] * C4 + t]);
    }
}

extern "C" void kernel_launch(void* const* d_in, const int* in_sizes, int n_in,
                              void* d_out, int out_size, void* d_ws, size_t ws_size,
                              hipStream_t stream) {
    const float* x    = (const float*)d_in[0];   // (B,N,C) fp32
    const float* W    = (const float*)d_in[1];   // (4,C)   fp32
    const float* bias = (const float*)d_in[2];   // (4,)    fp32
    float* out = (float*)d_out;

    f32x4* partW = (f32x4*)d_ws;                 // BB*NCHUNK f32x4 = 16 KB

    pool_dot<<<BB * NCHUNK, 192, 0, stream>>>((const f32x4*)x, (const f32x4*)W, partW);
    merge<<<BB * MBLK, 192, 0, stream>>>((const f32x4*)x, partW,
                                         (const f32x4*)bias, (f32x4*)out);
}

// Round 6
// 194.166 us; speedup vs baseline: 1.0057x; 1.0057x over previous
//
#include <hip/hip_runtime.h>
#include <hip/hip_cooperative_groups.h>

namespace cg = cooperative_groups;

// Problem constants (B,N,C) = (32,1024,768), H=32
#define BB 32
#define NN 1024
#define CC 768
#define HH 32
#define C4 (CC / 4)            // 192 float4 per row
#define NTHR 192
#define QPB 8                  // quads per block
#define BLKB 32                // blocks per batch (256 quads / 8)
#define GRID (BB * BLKB)       // 1024 blocks = 4/CU at 3 waves/SIMD
#define NCHUNK 32
#define NPER (NN / NCHUNK)
#define NORB 272
#define OPB 4
#define MBLK (NORB / OPB)

typedef float f32x4 __attribute__((ext_vector_type(4)));

// Quad enumeration. Per batch: 256 quads of 4 DISTINCT rows, covering every
// row exactly once:
//   q in [0,240): full orbit (r,c), 0<=r<c, r+c<31 -> rows {l, T(l), R(l), TR(l)}
//   q in [240,256): i=q-240: diag pair {33i, 1023-33i} + anti pair {31(i+1), 992-31i}
// All inputs block-uniform -> compiler puts these in SGPRs (cheap to recompute).
__device__ __forceinline__ void quad_rows(int jb, int u, int& r0, int& r1, int& r2, int& r3) {
    if (jb < 30) {
        const int q = jb * QPB + u;
        int r = 0;
#pragma unroll
        for (int rr = 1; rr <= 14; ++rr) if (rr * (31 - rr) <= q) r = rr;
        const int c = (r + 1) + (q - r * (31 - r));
        r0 = r * HH + c;          // l
        r1 = c * HH + r;          // T(l)
        r2 = (NN - 1) - r0;       // R(l)
        r3 = (NN - 1) - r1;       // TR(l)
    } else {
        const int i = (jb - 30) * QPB + u;   // 0..15
        r0 = 33 * i;              // diag l        (T(l)=l,  R(l)=r1)
        r1 = 1023 - 33 * i;       // diag reverse
        r2 = 31 * (i + 1);        // anti l        (T(l)=r3, R(l)=r3, TR(l)=l)
        r3 = 992 - 31 * i;        // anti transpose
    }
}

// ---------------------------------------------------------------------------
// Cooperative single-pass kernel: x is read from HBM EXACTLY ONCE.
// Phase 1: each block loads its 32 rows into registers (32 f32x4/thread),
//          sums them, dots with W -> per-block partial alpha (ws).
// grid.sync()
// Phase 2: reduce the 32 partials of this batch (512 B, L2-hot), form alpha,
//          combine the register-held rows, nontemporal-store output.
// ---------------------------------------------------------------------------
__global__ __launch_bounds__(NTHR, 3) void fused(const f32x4* __restrict__ x4,
                                                 const f32x4* __restrict__ W4,
                                                 const f32x4* __restrict__ bias4,
                                                 f32x4* __restrict__ partW4,
                                                 f32x4* __restrict__ o4) {
    const int blk = blockIdx.x;
    const int b   = blk >> 5;            // batch
    const int jb  = blk & 31;            // block-in-batch
    const int t   = threadIdx.x;         // 0..191 (c4)

    const f32x4* xb = x4 + (size_t)b * (NN * C4);

    // ---- phase 1: load 8 quads (32 rows) into registers ----
    f32x4 v[QPB][4];
#pragma unroll
    for (int u = 0; u < QPB; ++u) {
        int r0, r1, r2, r3; quad_rows(jb, u, r0, r1, r2, r3);
        v[u][0] = xb[(size_t)r0 * C4 + t];
        v[u][1] = xb[(size_t)r1 * C4 + t];
        v[u][2] = xb[(size_t)r2 * C4 + t];
        v[u][3] = xb[(size_t)r3 * C4 + t];
    }

    f32x4 s = {0.f, 0.f, 0.f, 0.f};
#pragma unroll
    for (int u = 0; u < QPB; ++u)
#pragma unroll
        for (int m = 0; m < 4; ++m) s += v[u][m];

    float d[4];
#pragma unroll
    for (int k = 0; k < 4; ++k) {
        const f32x4 w = W4[k * C4 + t];
        d[k] = s.x * w.x + s.y * w.y + s.z * w.z + s.w * w.w;
    }
    const int lane = t & 63;
    const int wid  = t >> 6;
    __shared__ float red[3][4];
#pragma unroll
    for (int k = 0; k < 4; ++k) {
        float r = d[k];
#pragma unroll
        for (int off = 32; off >= 1; off >>= 1) r += __shfl_down(r, off);
        if (lane == 0) red[wid][k] = r;
    }
    __syncthreads();
    if (t == 0) {
        f32x4 w;
        w.x = red[0][0] + red[1][0] + red[2][0];
        w.y = red[0][1] + red[1][1] + red[2][1];
        w.z = red[0][2] + red[1][2] + red[2][2];
        w.w = red[0][3] + red[1][3] + red[2][3];
        partW4[blk] = w;
    }

    cg::this_grid().sync();

    // ---- phase 2: alpha, combine, store ----
    f32x4 acc = {0.f, 0.f, 0.f, 0.f};
#pragma unroll 8
    for (int ch = 0; ch < BLKB; ++ch) acc += partW4[b * BLKB + ch];
    const f32x4 al = acc * (1.0f / (float)NN) + bias4[0];
    const float a0 = al.x, a1 = al.y, a2 = al.z, a3 = al.w;

    f32x4* ob = o4 + (size_t)b * (NN * C4);
    if (jb < 30) {
#pragma unroll
        for (int u = 0; u < QPB; ++u) {
            int r0, r1, r2, r3; quad_rows(jb, u, r0, r1, r2, r3);
            __builtin_nontemporal_store(a0*v[u][0] + a1*v[u][1] + a2*v[u][2] + a3*v[u][3], &ob[(size_t)r0 * C4 + t]);
            __builtin_nontemporal_store(a0*v[u][1] + a1*v[u][0] + a2*v[u][3] + a3*v[u][2], &ob[(size_t)r1 * C4 + t]);
            __builtin_nontemporal_store(a0*v[u][2] + a1*v[u][3] + a2*v[u][0] + a3*v[u][1], &ob[(size_t)r2 * C4 + t]);
            __builtin_nontemporal_store(a0*v[u][3] + a1*v[u][2] + a2*v[u][1] + a3*v[u][0], &ob[(size_t)r3 * C4 + t]);
        }
    } else {
        // diag rows: T(l)=l, R(l)=TR(l)=partner ; anti rows: T(l)=R(l)=partner, TR(l)=l
        const float p01 = a0 + a1, p23 = a2 + a3, p03 = a0 + a3, p12 = a1 + a2;
#pragma unroll
        for (int u = 0; u < QPB; ++u) {
            int r0, r1, r2, r3; quad_rows(jb, u, r0, r1, r2, r3);
            __builtin_nontemporal_store(p01*v[u][0] + p23*v[u][1], &ob[(size_t)r0 * C4 + t]);
            __builtin_nontemporal_store(p01*v[u][1] + p23*v[u][0], &ob[(size_t)r1 * C4 + t]);
            __builtin_nontemporal_store(p03*v[u][2] + p12*v[u][3], &ob[(size_t)r2 * C4 + t]);
            __builtin_nontemporal_store(p03*v[u][3] + p12*v[u][2], &ob[(size_t)r3 * C4 + t]);
        }
    }
}

// ---------------------------------------------------------------------------
// Fallback path (proven round-5 kernels) if cooperative launch is unavailable.
// ---------------------------------------------------------------------------
__global__ void pool_dot(const f32x4* __restrict__ x4,
                         const f32x4* __restrict__ W4,
                         f32x4* __restrict__ partW4) {
    const int blk = blockIdx.x;
    const int t   = threadIdx.x;
    const f32x4* xb = x4 + (size_t)blk * (NPER * C4) + t;
    f32x4 s = {0.f, 0.f, 0.f, 0.f};
#pragma unroll 8
    for (int n = 0; n < NPER; ++n) s += xb[(size_t)n * C4];
    float d[4];
#pragma unroll
    for (int k = 0; k < 4; ++k) {
        const f32x4 w = W4[k * C4 + t];
        d[k] = s.x * w.x + s.y * w.y + s.z * w.z + s.w * w.w;
    }
    const int lane = t & 63;
    const int wid  = t >> 6;
    __shared__ float red[3][4];
#pragma unroll
    for (int k = 0; k < 4; ++k) {
        float r = d[k];
#pragma unroll
        for (int off = 32; off >= 1; off >>= 1) r += __shfl_down(r, off);
        if (lane == 0) red[wid][k] = r;
    }
    __syncthreads();
    if (t == 0) {
        f32x4 w;
        w.x = red[0][0] + red[1][0] + red[2][0];
        w.y = red[0][1] + red[1][1] + red[2][1];
        w.z = red[0][2] + red[1][2] + red[2][2];
        w.w = red[0][3] + red[1][3] + red[2][3];
        partW4[blk] = w;
    }
}

__global__ void merge(const f32x4* __restrict__ x4,
                      const f32x4* __restrict__ partW4,
                      const f32x4* __restrict__ bias4,
                      f32x4* __restrict__ o4) {
    const int bidx = blockIdx.x;
    const int b = bidx / MBLK;
    const int j = bidx - b * MBLK;
    f32x4 acc = {0.f, 0.f, 0.f, 0.f};
#pragma unroll 8
    for (int ch = 0; ch < NCHUNK; ++ch) acc += partW4[b * NCHUNK + ch];
    const f32x4 al = acc * (1.0f / (float)NN) + bias4[0];
    const float a0 = al.x, a1 = al.y, a2 = al.z, a3 = al.w;
    const int t = threadIdx.x;
    const f32x4* xb = x4 + (size_t)b * (NN * C4);
    f32x4* ob = o4 + (size_t)b * (NN * C4);
    int L[OPB][4];
#pragma unroll
    for (int q = 0; q < OPB; ++q) {
        const int o = OPB * j + q;
        int r = 0;
#pragma unroll
        for (int rr = 1; rr <= 15; ++rr) if (rr * (33 - rr) <= o) r = rr;
        const int c = r + (o - r * (33 - r));
        L[q][0] = r * HH + c;
        L[q][1] = c * HH + r;
        L[q][2] = (NN - 1) - L[q][0];
        L[q][3] = (NN - 1) - L[q][1];
    }
    f32x4 v[OPB][4];
#pragma unroll
    for (int q = 0; q < OPB; ++q)
#pragma unroll
        for (int m = 0; m < 4; ++m)
            v[q][m] = xb[(size_t)L[q][m] * C4 + t];
#pragma unroll
    for (int q = 0; q < OPB; ++q) {
        __builtin_nontemporal_store(a0*v[q][0] + a1*v[q][1] + a2*v[q][2] + a3*v[q][3], &ob[(size_t)L[q][0] * C4 + t]);
        __builtin_nontemporal_store(a0*v[q][1] + a1*v[q][0] + a2*v[q][3] + a3*v[q][2], &ob[(size_t)L[q][1] * C4 + t]);
        __builtin_nontemporal_store(a0*v[q][2] + a1*v[q][3] + a2*v[q][0] + a3*v[q][1], &ob[(size_t)L[q][2] * C4 + t]);
        __builtin_nontemporal_store(a0*v[q][3] + a1*v[q][2] + a2*v[q][1] + a3*v[q][0], &ob[(size_t)L[q][3] * C4 + t]);
    }
}

extern "C" void kernel_launch(void* const* d_in, const int* in_sizes, int n_in,
                              void* d_out, int out_size, void* d_ws, size_t ws_size,
                              hipStream_t stream) {
    const f32x4* x4p = (const f32x4*)d_in[0];   // (B,N,C) fp32
    const f32x4* W4p = (const f32x4*)d_in[1];   // (4,C)   fp32
    const f32x4* b4p = (const f32x4*)d_in[2];   // (4,)    fp32
    f32x4* o4p = (f32x4*)d_out;
    f32x4* pw  = (f32x4*)d_ws;                  // GRID f32x4 = 16 KB

    // Deterministic capability check (pure query, graph-capture-safe):
    int maxB = 0;
    hipError_t qerr = hipOccupancyMaxActiveBlocksPerMultiprocessor(&maxB, fused, NTHR, 0);
    if (qerr == hipSuccess && maxB * 256 >= GRID) {
        void* args[5] = {(void*)&x4p, (void*)&W4p, (void*)&b4p, (void*)&pw, (void*)&o4p};
        hipError_t err = hipLaunchCooperativeKernel((const void*)fused, dim3(GRID), dim3(NTHR),
                                                    args, 0, stream);
        if (err == hipSuccess) return;
    }
    // Fallback: proven two-kernel path.
    pool_dot<<<BB * NCHUNK, NTHR, 0, stream>>>(x4p, W4p, pw);
    merge<<<BB * MBLK, NTHR, 0, stream>>>(x4p, pw, b4p, o4p);
}